// Round 2
// baseline (169.537 us; speedup 1.0000x reference)
//
#include <hip/hip_runtime.h>

namespace {

constexpr int NN  = 256;             // FFT length along each axis
constexpr int BMN = 256 * 256 * 256; // elements per component

struct cpx { float re, im; };

__device__ __forceinline__ cpx cadd(cpx a, cpx b){ return cpx{a.re + b.re, a.im + b.im}; }
__device__ __forceinline__ cpx csub(cpx a, cpx b){ return cpx{a.re - b.re, a.im - b.im}; }
__device__ __forceinline__ cpx cmul(cpx a, cpx b){ return cpx{a.re*b.re - a.im*b.im, a.re*b.im + a.im*b.re}; }
__device__ __forceinline__ cpx cmuli(cpx a){ return cpx{-a.im, a.re}; }  // multiply by +i (inverse transform)

// radix-4 inverse butterfly: y[k] = sum_n x[n] * e^{+2pi i nk/4}
__device__ __forceinline__ void r4(cpx a, cpx b, cpx c, cpx d,
                                   cpx& y0, cpx& y1, cpx& y2, cpx& y3) {
  cpx apc = cadd(a, c), amc = csub(a, c);
  cpx bpd = cadd(b, d), bmd = csub(b, d);
  cpx ib  = cmuli(bmd);
  y0 = cadd(apc, bpd);
  y1 = cadd(amc, ib);
  y2 = csub(apc, bpd);
  y3 = csub(amc, ib);
}

// 16-point inverse DFT (unnormalized), natural order in/out, fully in registers.
__device__ __forceinline__ void ifft16(cpx x[16]) {
  constexpr float WC[10] = { 1.f,  0.9238795325112867f,  0.7071067811865476f,  0.3826834323650898f, 0.f,
                            -0.3826834323650898f, -0.7071067811865476f, -0.9238795325112867f, -1.f,
                            -0.9238795325112867f };
  constexpr float WS[10] = { 0.f,  0.3826834323650898f,  0.7071067811865476f,  0.9238795325112867f, 1.f,
                             0.9238795325112867f,  0.7071067811865476f,  0.3826834323650898f,  0.f,
                            -0.3826834323650898f };
  cpx B[4][4];
#pragma unroll
  for (int n1 = 0; n1 < 4; ++n1)
    r4(x[n1], x[n1 + 4], x[n1 + 8], x[n1 + 12],
       B[n1][0], B[n1][1], B[n1][2], B[n1][3]);
#pragma unroll
  for (int n1 = 1; n1 < 4; ++n1)
#pragma unroll
    for (int k2 = 1; k2 < 4; ++k2)
      B[n1][k2] = cmul(B[n1][k2], cpx{WC[n1 * k2], WS[n1 * k2]});
#pragma unroll
  for (int k2 = 0; k2 < 4; ++k2)
    r4(B[0][k2], B[1][k2], B[2][k2], B[3][k2],
       x[k2], x[k2 + 4], x[k2 + 8], x[k2 + 12]);
}

// multiply a[k1] by W256^{t*k1} = e^{+2pi i t k1/256}
__device__ __forceinline__ void twiddle256(cpx a[16], int t) {
  const float base = 0.024543692606170259f * (float)t;  // 2*pi/256 * t
#pragma unroll
  for (int k1 = 1; k1 < 16; ++k1) {
    float s, c;
    __sincosf(base * (float)k1, &s, &c);
    a[k1] = cmul(a[k1], cpx{c, s});
  }
}

// two-pass 16x16 transpose through a single float buffer (re then im).
// L is this group's 272-float slice. t = in-group lane (0..15).
// Entry: a[k1] = value[k1][t]. Exit: a[n2] = value[t][n2].
__device__ __forceinline__ void transpose16(cpx a[16], float* L, int t) {
#pragma unroll
  for (int k1 = 0; k1 < 16; ++k1) L[k1 * 17 + t] = a[k1].re;
  __syncthreads();
  float br[16];
#pragma unroll
  for (int n2 = 0; n2 < 16; ++n2) br[n2] = L[t * 17 + n2];
  __syncthreads();
#pragma unroll
  for (int k1 = 0; k1 < 16; ++k1) L[k1 * 17 + t] = a[k1].im;
  __syncthreads();
#pragma unroll
  for (int n2 = 0; n2 < 16; ++n2) { a[n2].im = L[t * 17 + n2]; a[n2].re = br[n2]; }
}

// ------- kernel 1: IFFT along last axis (contiguous), shifts folded in -------
// line = b*256 + m. 16 threads per line (t = n2), 16 lines per block.
// LDS: single float buffer 16*272*4B = 17.4KB -> 8 blocks/CU (32 waves/CU).
__global__ __launch_bounds__(256, 8)
void k_ifft_rows(const float* __restrict__ xr, const float* __restrict__ xi,
                 float* __restrict__ yr, float* __restrict__ yi) {
  __shared__ float lbuf[16 * 272];
  const int tid  = threadIdx.x;
  const int t    = tid & 15;
  const int ll   = tid >> 4;
  const int line = blockIdx.x * 16 + ll;
  const float* pr = xr + line * NN;
  const float* pi = xi + line * NN;

  cpx a[16];
#pragma unroll
  for (int j = 0; j < 16; ++j) {
    const int idx = (((j << 4) | t) ^ 128);   // ifftshift on load
    a[j] = cpx{ pr[idx], pi[idx] };
  }
  ifft16(a);            // a[k1] = A[k1][n2=t]
  twiddle256(a, t);     // * W256^{t*k1}

  transpose16(a, lbuf + ll * 272, t);

  ifft16(a);            // a[k2] = X[t + 16*k2]
  float* qr = yr + line * NN;
  float* qi = yi + line * NN;
#pragma unroll
  for (int k = 0; k < 16; ++k) {
    const int idx = (((k << 4) | t) ^ 128);   // fftshift on store
    qr[idx] = a[k].re;
    qi[idx] = a[k].im;
  }
}

// ------- kernel 2: IFFT along axis -2 (stride 256), in-place on d_out -------
__global__ __launch_bounds__(256, 8)
void k_ifft_cols(float* __restrict__ yr, float* __restrict__ yi) {
  __shared__ float lbuf[16 * 272];
  const int tid = threadIdx.x;
  const int c   = tid & 15;
  const int t   = tid >> 4;
  const int b   = blockIdx.x >> 4;
  const int c0  = (blockIdx.x & 15) << 4;
  const int base = b * 65536 + c0 + c;

  cpx a[16];
#pragma unroll
  for (int j = 0; j < 16; ++j) {
    const int m = (((j << 4) | t) ^ 128);     // ifftshift on load
    a[j] = cpx{ yr[base + m * NN], yi[base + m * NN] };
  }
  ifft16(a);
  twiddle256(a, t);

  transpose16(a, lbuf + c * 272, t);

  ifft16(a);
  constexpr float sc = 1.0f / 65536.0f;       // ifft2 normalization
#pragma unroll
  for (int k = 0; k < 16; ++k) {
    const int m = (((k << 4) | t) ^ 128);     // fftshift on store
    yr[base + m * NN] = a[k].re * sc;
    yi[base + m * NN] = a[k].im * sc;
  }
}

} // namespace

extern "C" void kernel_launch(void* const* d_in, const int* in_sizes, int n_in,
                              void* d_out, int out_size, void* d_ws, size_t ws_size,
                              hipStream_t stream) {
  const float* xr = (const float*)d_in[0];
  const float* xi = (const float*)d_in[1];
  float* yr = (float*)d_out;        // real part of output
  float* yi = yr + BMN;             // imag part of output

  k_ifft_rows<<<4096, 256, 0, stream>>>(xr, xi, yr, yi);
  k_ifft_cols<<<4096, 256, 0, stream>>>(yr, yi);
}

// Round 3
// 86.946 us; speedup vs baseline: 1.9499x; 1.9499x over previous
//
#include <hip/hip_runtime.h>

namespace {

constexpr int NN  = 256;             // FFT length along each axis
constexpr int BMN = 256 * 256 * 256; // elements per component

struct cpx { float re, im; };

__device__ __forceinline__ cpx cadd(cpx a, cpx b){ return cpx{a.re + b.re, a.im + b.im}; }
__device__ __forceinline__ cpx csub(cpx a, cpx b){ return cpx{a.re - b.re, a.im - b.im}; }
__device__ __forceinline__ cpx cmul(cpx a, cpx b){ return cpx{a.re*b.re - a.im*b.im, a.re*b.im + a.im*b.re}; }
__device__ __forceinline__ cpx cmuli(cpx a){ return cpx{-a.im, a.re}; }  // multiply by +i (inverse)

// radix-4 inverse butterfly: y[k] = sum_n x[n] * e^{+2pi i nk/4}
__device__ __forceinline__ void r4(cpx a, cpx b, cpx c, cpx d,
                                   cpx& y0, cpx& y1, cpx& y2, cpx& y3) {
  cpx apc = cadd(a, c), amc = csub(a, c);
  cpx bpd = cadd(b, d), bmd = csub(b, d);
  cpx ib  = cmuli(bmd);
  y0 = cadd(apc, bpd);
  y1 = cadd(amc, ib);
  y2 = csub(apc, bpd);
  y3 = csub(amc, ib);
}

// 16-point inverse DFT (unnormalized), natural order in/out, in registers.
__device__ __forceinline__ void ifft16(cpx x[16]) {
  constexpr float WC[10] = { 1.f,  0.9238795325112867f,  0.7071067811865476f,  0.3826834323650898f, 0.f,
                            -0.3826834323650898f, -0.7071067811865476f, -0.9238795325112867f, -1.f,
                            -0.9238795325112867f };
  constexpr float WS[10] = { 0.f,  0.3826834323650898f,  0.7071067811865476f,  0.9238795325112867f, 1.f,
                             0.9238795325112867f,  0.7071067811865476f,  0.3826834323650898f,  0.f,
                            -0.3826834323650898f };
  cpx B[4][4];
#pragma unroll
  for (int n1 = 0; n1 < 4; ++n1)
    r4(x[n1], x[n1 + 4], x[n1 + 8], x[n1 + 12],
       B[n1][0], B[n1][1], B[n1][2], B[n1][3]);
#pragma unroll
  for (int n1 = 1; n1 < 4; ++n1)
#pragma unroll
    for (int k2 = 1; k2 < 4; ++k2)
      B[n1][k2] = cmul(B[n1][k2], cpx{WC[n1 * k2], WS[n1 * k2]});
#pragma unroll
  for (int k2 = 0; k2 < 4; ++k2)
    r4(B[0][k2], B[1][k2], B[2][k2], B[3][k2],
       x[k2], x[k2 + 4], x[k2 + 8], x[k2 + 12]);
}

// multiply a[k1] by W256^{t*k1} = e^{+2pi i t k1/256}
__device__ __forceinline__ void twiddle256(cpx a[16], int t) {
  const float base = 0.024543692606170259f * (float)t;  // 2*pi/256 * t
#pragma unroll
  for (int k1 = 1; k1 < 16; ++k1) {
    float s, c;
    __sincosf(base * (float)k1, &s, &c);
    a[k1] = cmul(a[k1], cpx{c, s});
  }
}

// two-pass 16x16 transpose through a single float slice (re then im).
// L = this group's slice (group stride 273 floats, row stride 17 inside).
// Entry: a[k1] = val[k1][t]. Exit: a[n2] = val[t][n2].
// Peak live regs: a[].im (16) + br (16) -> ~50 total; MUST NOT be
// register-capped by launch_bounds min-waves or it spills (round-2 lesson).
__device__ __forceinline__ void transpose16(cpx a[16], float* L, int t) {
#pragma unroll
  for (int k1 = 0; k1 < 16; ++k1) L[k1 * 17 + t] = a[k1].re;
  __syncthreads();
  float br[16];
#pragma unroll
  for (int n2 = 0; n2 < 16; ++n2) br[n2] = L[t * 17 + n2];
  __syncthreads();
#pragma unroll
  for (int k1 = 0; k1 < 16; ++k1) L[k1 * 17 + t] = a[k1].im;
  __syncthreads();
#pragma unroll
  for (int n2 = 0; n2 < 16; ++n2) { a[n2].im = L[t * 17 + n2]; a[n2].re = br[n2]; }
}

// ------- kernel 1: IFFT along last axis (contiguous), shifts folded in -------
// line = b*256 + m. 16 threads per line (t), 16 lines per block (ll).
// LDS 16*273*4 = 17472 B -> up to 9 blocks/CU by LDS; occupancy set by VGPR.
__global__ __launch_bounds__(256)
void k_ifft_rows(const float* __restrict__ xr, const float* __restrict__ xi,
                 float* __restrict__ yr, float* __restrict__ yi) {
  __shared__ float lbuf[16 * 273];
  const int tid  = threadIdx.x;
  const int t    = tid & 15;
  const int ll   = tid >> 4;
  const int line = blockIdx.x * 16 + ll;
  const float* pr = xr + line * NN;
  const float* pi = xi + line * NN;

  cpx a[16];
#pragma unroll
  for (int j = 0; j < 16; ++j) {
    const int idx = (((j << 4) | t) ^ 128);   // ifftshift on load
    a[j] = cpx{ pr[idx], pi[idx] };
  }
  ifft16(a);            // a[k1] = A_t[k1]
  twiddle256(a, t);     // * W256^{t*k1}

  transpose16(a, lbuf + ll * 273, t);

  ifft16(a);            // a[k2] = X[16*k2 + t]
  float* qr = yr + line * NN;
  float* qi = yi + line * NN;
#pragma unroll
  for (int k = 0; k < 16; ++k) {
    const int idx = (((k << 4) | t) ^ 128);   // fftshift on store
    qr[idx] = a[k].re;
    qi[idx] = a[k].im;
  }
}

// ------- kernel 2: IFFT along axis -2 (stride 256), in-place on d_out -------
// 512 threads: c = tid&31 (column, lane-fastest -> 128B contiguous segments),
// t = tid>>5 (position group). 32-column tiles, 8 tiles/image.
// LDS 32*273*4 = 34944 B -> 4 blocks/CU by LDS (32 waves = 100% if VGPR<=64).
__global__ __launch_bounds__(512)
void k_ifft_cols(float* __restrict__ yr, float* __restrict__ yi) {
  __shared__ float lbuf[32 * 273];
  const int tid = threadIdx.x;
  const int c   = tid & 31;
  const int t   = tid >> 5;
  const int b   = blockIdx.x >> 3;
  const int c0  = (blockIdx.x & 7) << 5;
  const int base = b * 65536 + c0 + c;

  cpx a[16];
#pragma unroll
  for (int j = 0; j < 16; ++j) {
    const int m = (((j << 4) | t) ^ 128);     // ifftshift on load
    a[j] = cpx{ yr[base + m * NN], yi[base + m * NN] };
  }
  ifft16(a);
  twiddle256(a, t);

  transpose16(a, lbuf + c * 273, t);

  ifft16(a);
  constexpr float sc = 1.0f / 65536.0f;       // ifft2 normalization
#pragma unroll
  for (int k = 0; k < 16; ++k) {
    const int m = (((k << 4) | t) ^ 128);     // fftshift on store
    yr[base + m * NN] = a[k].re * sc;
    yi[base + m * NN] = a[k].im * sc;
  }
}

} // namespace

extern "C" void kernel_launch(void* const* d_in, const int* in_sizes, int n_in,
                              void* d_out, int out_size, void* d_ws, size_t ws_size,
                              hipStream_t stream) {
  const float* xr = (const float*)d_in[0];
  const float* xi = (const float*)d_in[1];
  float* yr = (float*)d_out;        // real part of output
  float* yi = yr + BMN;             // imag part of output

  k_ifft_rows<<<4096, 256, 0, stream>>>(xr, xi, yr, yi);   // 65536 lines / 16
  k_ifft_cols<<<2048, 512, 0, stream>>>(yr, yi);           // 256 images * 8 tiles
}

// Round 4
// 86.543 us; speedup vs baseline: 1.9590x; 1.0047x over previous
//
#include <hip/hip_runtime.h>

namespace {

constexpr int NN   = 256;             // FFT length along each axis
constexpr int BMN  = 256 * 256 * 256; // elements per component
constexpr int LPAD = 272;             // padded float stride per line slice (68 float4)

struct cpx { float re, im; };

__device__ __forceinline__ cpx cadd(cpx a, cpx b){ return cpx{a.re + b.re, a.im + b.im}; }
__device__ __forceinline__ cpx csub(cpx a, cpx b){ return cpx{a.re - b.re, a.im - b.im}; }
__device__ __forceinline__ cpx cmul(cpx a, cpx b){ return cpx{a.re*b.re - a.im*b.im, a.re*b.im + a.im*b.re}; }
__device__ __forceinline__ cpx cmuli(cpx a){ return cpx{-a.im, a.re}; }  // multiply by +i (inverse)

// radix-4 inverse butterfly: y[k] = sum_n x[n] * e^{+2pi i nk/4}
__device__ __forceinline__ void r4(cpx a, cpx b, cpx c, cpx d,
                                   cpx& y0, cpx& y1, cpx& y2, cpx& y3) {
  cpx apc = cadd(a, c), amc = csub(a, c);
  cpx bpd = cadd(b, d), bmd = csub(b, d);
  cpx ib  = cmuli(bmd);
  y0 = cadd(apc, bpd);
  y1 = cadd(amc, ib);
  y2 = csub(apc, bpd);
  y3 = csub(amc, ib);
}

// 16-point inverse DFT (unnormalized), natural order in/out, in registers.
__device__ __forceinline__ void ifft16(cpx x[16]) {
  constexpr float WC[10] = { 1.f,  0.9238795325112867f,  0.7071067811865476f,  0.3826834323650898f, 0.f,
                            -0.3826834323650898f, -0.7071067811865476f, -0.9238795325112867f, -1.f,
                            -0.9238795325112867f };
  constexpr float WS[10] = { 0.f,  0.3826834323650898f,  0.7071067811865476f,  0.9238795325112867f, 1.f,
                             0.9238795325112867f,  0.7071067811865476f,  0.3826834323650898f,  0.f,
                            -0.3826834323650898f };
  cpx B[4][4];
#pragma unroll
  for (int n1 = 0; n1 < 4; ++n1)
    r4(x[n1], x[n1 + 4], x[n1 + 8], x[n1 + 12],
       B[n1][0], B[n1][1], B[n1][2], B[n1][3]);
#pragma unroll
  for (int n1 = 1; n1 < 4; ++n1)
#pragma unroll
    for (int k2 = 1; k2 < 4; ++k2)
      B[n1][k2] = cmul(B[n1][k2], cpx{WC[n1 * k2], WS[n1 * k2]});
#pragma unroll
  for (int k2 = 0; k2 < 4; ++k2)
    r4(B[0][k2], B[1][k2], B[2][k2], B[3][k2],
       x[k2], x[k2 + 4], x[k2 + 8], x[k2 + 12]);
}

// multiply a[k1] by W256^{t*k1} = e^{+2pi i t k1/256}
__device__ __forceinline__ void twiddle256(cpx a[16], int t) {
  const float base = 0.024543692606170259f * (float)t;  // 2*pi/256 * t
#pragma unroll
  for (int k1 = 1; k1 < 16; ++k1) {
    float s, c;
    __sincosf(base * (float)k1, &s, &c);
    a[k1] = cmul(a[k1], cpx{c, s});
  }
}

// ------- kernel 1: IFFT along last axis (contiguous), shifts folded in -------
// 16 lines/block, 256 threads. ALL global I/O is cooperative float4
// (each wave instruction = 1KB contiguous); the stride-16 comb and the
// 16x16 transpose are redistributed through LDS.
// LDS: 2 x 16 x 272 floats = 34.8KB -> 4 blocks/CU.
// NOTE: no min-waves launch bound — forcing 8 made the allocator spill
// (round-2 lesson: VGPR capped at 32 -> +250MB scratch traffic).
__global__ __launch_bounds__(256)
void k_ifft_rows(const float* __restrict__ xr, const float* __restrict__ xi,
                 float* __restrict__ yr, float* __restrict__ yi) {
  __shared__ float Lr[16 * LPAD];
  __shared__ float Li[16 * LPAD];
  const int tid = threadIdx.x;
  const int t   = tid & 15;
  const int ll  = tid >> 4;

  const size_t blk = (size_t)blockIdx.x * (16 * NN);
  const float4* sr4 = reinterpret_cast<const float4*>(xr + blk);
  const float4* si4 = reinterpret_cast<const float4*>(xi + blk);

  // --- cooperative vector load: fi = q*256 + tid (lane-fastest => contiguous)
#pragma unroll
  for (int q = 0; q < 4; ++q) {
    const int fi   = (q << 8) + tid;
    const int line = fi >> 6;
    const int slot = fi & 63;
    *reinterpret_cast<float4*>(&Lr[line * LPAD + slot * 4]) = sr4[fi];
    *reinterpret_cast<float4*>(&Li[line * LPAD + slot * 4]) = si4[fi];
  }
  __syncthreads();

  // --- comb read (ifftshift folded): a[j] = x[(j*16+t)^128] of line ll
  cpx a[16];
  {
    const float* lr = Lr + ll * LPAD;
    const float* li = Li + ll * LPAD;
#pragma unroll
    for (int j = 0; j < 16; ++j) {
      const int idx = (((j << 4) | t) ^ 128);
      a[j] = cpx{ lr[idx], li[idx] };
    }
  }
  ifft16(a);            // a[k1] = A_t[k1]
  twiddle256(a, t);     // * W256^{t*k1}
  __syncthreads();      // before overwriting staged data

  // --- 16x16 transpose (single pass, both components)
  {
    float* lr = Lr + ll * LPAD;
    float* li = Li + ll * LPAD;
#pragma unroll
    for (int k1 = 0; k1 < 16; ++k1) { lr[k1 * 17 + t] = a[k1].re; li[k1 * 17 + t] = a[k1].im; }
    __syncthreads();
#pragma unroll
    for (int n2 = 0; n2 < 16; ++n2) { a[n2].re = lr[t * 17 + n2]; a[n2].im = li[t * 17 + n2]; }
  }
  ifft16(a);            // a[k2] = X[16*k2 + t]
  __syncthreads();      // before overwriting transpose data

  // --- stage output in natural line layout (fftshift folded)
  {
    float* lr = Lr + ll * LPAD;
    float* li = Li + ll * LPAD;
#pragma unroll
    for (int k = 0; k < 16; ++k) {
      const int idx = (((k << 4) | t) ^ 128);
      lr[idx] = a[k].re;
      li[idx] = a[k].im;
    }
  }
  __syncthreads();

  // --- cooperative vector store
  float4* dr4 = reinterpret_cast<float4*>(yr + blk);
  float4* di4 = reinterpret_cast<float4*>(yi + blk);
#pragma unroll
  for (int q = 0; q < 4; ++q) {
    const int fi   = (q << 8) + tid;
    const int line = fi >> 6;
    const int slot = fi & 63;
    dr4[fi] = *reinterpret_cast<const float4*>(&Lr[line * LPAD + slot * 4]);
    di4[fi] = *reinterpret_cast<const float4*>(&Li[line * LPAD + slot * 4]);
  }
}

// ------- kernel 2: IFFT along axis -2 (stride 256), in-place on d_out -------
// 512 threads: c = tid&31 (column, lane-fastest -> 128B contiguous segments),
// t = tid>>5 (position group). 32-column tiles, 8 tiles/image. (round-3, ~10us)
__global__ __launch_bounds__(512)
void k_ifft_cols(float* __restrict__ yr, float* __restrict__ yi) {
  __shared__ float lbuf[32 * 273];
  const int tid = threadIdx.x;
  const int c   = tid & 31;
  const int t   = tid >> 5;
  const int b   = blockIdx.x >> 3;
  const int c0  = (blockIdx.x & 7) << 5;
  const int base = b * 65536 + c0 + c;

  cpx a[16];
#pragma unroll
  for (int j = 0; j < 16; ++j) {
    const int m = (((j << 4) | t) ^ 128);     // ifftshift on load
    a[j] = cpx{ yr[base + m * NN], yi[base + m * NN] };
  }
  ifft16(a);
  twiddle256(a, t);

  // two-pass 16x16 transpose through single buffer (re then im)
  {
    float* L = lbuf + c * 273;
#pragma unroll
    for (int k1 = 0; k1 < 16; ++k1) L[k1 * 17 + t] = a[k1].re;
    __syncthreads();
    float br[16];
#pragma unroll
    for (int n2 = 0; n2 < 16; ++n2) br[n2] = L[t * 17 + n2];
    __syncthreads();
#pragma unroll
    for (int k1 = 0; k1 < 16; ++k1) L[k1 * 17 + t] = a[k1].im;
    __syncthreads();
#pragma unroll
    for (int n2 = 0; n2 < 16; ++n2) { a[n2].im = L[t * 17 + n2]; a[n2].re = br[n2]; }
  }

  ifft16(a);
  constexpr float sc = 1.0f / 65536.0f;       // ifft2 normalization
#pragma unroll
  for (int k = 0; k < 16; ++k) {
    const int m = (((k << 4) | t) ^ 128);     // fftshift on store
    yr[base + m * NN] = a[k].re * sc;
    yi[base + m * NN] = a[k].im * sc;
  }
}

} // namespace

extern "C" void kernel_launch(void* const* d_in, const int* in_sizes, int n_in,
                              void* d_out, int out_size, void* d_ws, size_t ws_size,
                              hipStream_t stream) {
  const float* xr = (const float*)d_in[0];
  const float* xi = (const float*)d_in[1];
  float* yr = (float*)d_out;        // real part of output
  float* yi = yr + BMN;             // imag part of output

  k_ifft_rows<<<4096, 256, 0, stream>>>(xr, xi, yr, yi);   // 65536 lines / 16
  k_ifft_cols<<<2048, 512, 0, stream>>>(yr, yi);           // 256 images * 8 tiles
}

// Round 5
// 79.327 us; speedup vs baseline: 2.1372x; 1.0910x over previous
//
#include <hip/hip_runtime.h>
#include <hip/hip_fp16.h>

namespace {

constexpr int NN   = 256;             // FFT length along each axis
constexpr int BMN  = 256 * 256 * 256; // elements per component
constexpr int LPAD = 272;             // padded float stride per line slice (16B-aligned: 68 float4)

struct cpx { float re, im; };

__device__ __forceinline__ cpx cadd(cpx a, cpx b){ return cpx{a.re + b.re, a.im + b.im}; }
__device__ __forceinline__ cpx csub(cpx a, cpx b){ return cpx{a.re - b.re, a.im - b.im}; }
__device__ __forceinline__ cpx cmul(cpx a, cpx b){ return cpx{a.re*b.re - a.im*b.im, a.re*b.im + a.im*b.re}; }
__device__ __forceinline__ cpx cmuli(cpx a){ return cpx{-a.im, a.re}; }  // multiply by +i (inverse)

// radix-4 inverse butterfly: y[k] = sum_n x[n] * e^{+2pi i nk/4}
__device__ __forceinline__ void r4(cpx a, cpx b, cpx c, cpx d,
                                   cpx& y0, cpx& y1, cpx& y2, cpx& y3) {
  cpx apc = cadd(a, c), amc = csub(a, c);
  cpx bpd = cadd(b, d), bmd = csub(b, d);
  cpx ib  = cmuli(bmd);
  y0 = cadd(apc, bpd);
  y1 = cadd(amc, ib);
  y2 = csub(apc, bpd);
  y3 = csub(amc, ib);
}

// 16-point inverse DFT (unnormalized), natural order in/out, in registers.
__device__ __forceinline__ void ifft16(cpx x[16]) {
  constexpr float WC[10] = { 1.f,  0.9238795325112867f,  0.7071067811865476f,  0.3826834323650898f, 0.f,
                            -0.3826834323650898f, -0.7071067811865476f, -0.9238795325112867f, -1.f,
                            -0.9238795325112867f };
  constexpr float WS[10] = { 0.f,  0.3826834323650898f,  0.7071067811865476f,  0.9238795325112867f, 1.f,
                             0.9238795325112867f,  0.7071067811865476f,  0.3826834323650898f,  0.f,
                            -0.3826834323650898f };
  cpx B[4][4];
#pragma unroll
  for (int n1 = 0; n1 < 4; ++n1)
    r4(x[n1], x[n1 + 4], x[n1 + 8], x[n1 + 12],
       B[n1][0], B[n1][1], B[n1][2], B[n1][3]);
#pragma unroll
  for (int n1 = 1; n1 < 4; ++n1)
#pragma unroll
    for (int k2 = 1; k2 < 4; ++k2)
      B[n1][k2] = cmul(B[n1][k2], cpx{WC[n1 * k2], WS[n1 * k2]});
#pragma unroll
  for (int k2 = 0; k2 < 4; ++k2)
    r4(B[0][k2], B[1][k2], B[2][k2], B[3][k2],
       x[k2], x[k2 + 4], x[k2 + 8], x[k2 + 12]);
}

// multiply a[k1] by W256^{t*k1} = e^{+2pi i t k1/256}
__device__ __forceinline__ void twiddle256(cpx a[16], int t) {
  const float base = 0.024543692606170259f * (float)t;  // 2*pi/256 * t
#pragma unroll
  for (int k1 = 1; k1 < 16; ++k1) {
    float s, c;
    __sincosf(base * (float)k1, &s, &c);
    a[k1] = cmul(a[k1], cpx{c, s});
  }
}

// ------- kernel 1: row IFFT (last axis). fp32 in -> fp16 intermediate in d_ws.
// 16 lines/block, 256 threads. Coalesced float4 loads via LDS; LDS transpose;
// output staged in LDS, converted to fp16 (scale 1/256) and stored coalesced.
// Intermediate is NOT nontemporal: we want it dirty-resident in L3 for cols.
__global__ __launch_bounds__(256)
void k_ifft_rows(const float* __restrict__ xr, const float* __restrict__ xi,
                 __half* __restrict__ wr, __half* __restrict__ wi) {
  __shared__ float Lr[16 * LPAD];
  __shared__ float Li[16 * LPAD];
  const int tid = threadIdx.x;
  const int t   = tid & 15;
  const int ll  = tid >> 4;

  const size_t blk = (size_t)blockIdx.x * (16 * NN);
  const float4* sr4 = reinterpret_cast<const float4*>(xr + blk);
  const float4* si4 = reinterpret_cast<const float4*>(xi + blk);

  // cooperative vector load (1KB contiguous per wave instruction)
#pragma unroll
  for (int q = 0; q < 4; ++q) {
    const int fi   = (q << 8) + tid;
    const int line = fi >> 6;
    const int slot = fi & 63;
    *reinterpret_cast<float4*>(&Lr[line * LPAD + slot * 4]) = sr4[fi];
    *reinterpret_cast<float4*>(&Li[line * LPAD + slot * 4]) = si4[fi];
  }
  __syncthreads();

  // comb read (ifftshift folded): a[j] = x[(j*16+t)^128] of line ll
  cpx a[16];
  {
    const float* lr = Lr + ll * LPAD;
    const float* li = Li + ll * LPAD;
#pragma unroll
    for (int j = 0; j < 16; ++j) {
      const int idx = (((j << 4) | t) ^ 128);
      a[j] = cpx{ lr[idx], li[idx] };
    }
  }
  ifft16(a);            // a[k1] = A_t[k1]
  twiddle256(a, t);     // * W256^{t*k1}
  __syncthreads();

  // 16x16 transpose (single pass, both components)
  {
    float* lr = Lr + ll * LPAD;
    float* li = Li + ll * LPAD;
#pragma unroll
    for (int k1 = 0; k1 < 16; ++k1) { lr[k1 * 17 + t] = a[k1].re; li[k1 * 17 + t] = a[k1].im; }
    __syncthreads();
#pragma unroll
    for (int n2 = 0; n2 < 16; ++n2) { a[n2].re = lr[t * 17 + n2]; a[n2].im = li[t * 17 + n2]; }
  }
  ifft16(a);            // a[k2] = X[16*k2 + t]
  __syncthreads();

  // stage output in natural line layout (fftshift folded)
  {
    float* lr = Lr + ll * LPAD;
    float* li = Li + ll * LPAD;
#pragma unroll
    for (int k = 0; k < 16; ++k) {
      const int idx = (((k << 4) | t) ^ 128);
      lr[idx] = a[k].re;
      li[idx] = a[k].im;
    }
  }
  __syncthreads();

  // cooperative convert+store fp16 (scale = half of the 1/65536 norm)
  constexpr float s1 = 1.0f / 256.0f;
  uint2* dr = reinterpret_cast<uint2*>(wr) + (size_t)blockIdx.x * 1024;
  uint2* di = reinterpret_cast<uint2*>(wi) + (size_t)blockIdx.x * 1024;
#pragma unroll
  for (int q = 0; q < 4; ++q) {
    const int fi   = (q << 8) + tid;
    const int line = fi >> 6;
    const int slot = fi & 63;
    const float4 vr = *reinterpret_cast<const float4*>(&Lr[line * LPAD + slot * 4]);
    const float4 vi = *reinterpret_cast<const float4*>(&Li[line * LPAD + slot * 4]);
    union { __half2 h[2]; uint2 u; } pr, pi_;
    pr.h[0]  = __floats2half2_rn(vr.x * s1, vr.y * s1);
    pr.h[1]  = __floats2half2_rn(vr.z * s1, vr.w * s1);
    pi_.h[0] = __floats2half2_rn(vi.x * s1, vi.y * s1);
    pi_.h[1] = __floats2half2_rn(vi.z * s1, vi.w * s1);
    dr[fi] = pr.u;
    di[fi] = pi_.u;
  }
}

// ------- kernel 2: column IFFT (axis -2). fp16 intermediate -> fp32 out.
// 512 threads: c = tid&31 (column, lane-fastest), t = tid>>5. 32-col tiles.
// Reads hit L3 (ws resident); final stores are NONTEMPORAL so the dead
// output doesn't evict input/ws from L3 across graph replays.
__global__ __launch_bounds__(512)
void k_ifft_cols(const __half* __restrict__ wr, const __half* __restrict__ wi,
                 float* __restrict__ yr, float* __restrict__ yi) {
  __shared__ float lbuf[32 * 273];
  const int tid = threadIdx.x;
  const int c   = tid & 31;
  const int t   = tid >> 5;
  const int b   = blockIdx.x >> 3;
  const int c0  = (blockIdx.x & 7) << 5;
  const int base = b * 65536 + c0 + c;

  cpx a[16];
#pragma unroll
  for (int j = 0; j < 16; ++j) {
    const int m = (((j << 4) | t) ^ 128);     // ifftshift on load
    a[j] = cpx{ __half2float(wr[base + m * NN]), __half2float(wi[base + m * NN]) };
  }
  ifft16(a);
  twiddle256(a, t);

  // two-pass 16x16 transpose through single buffer (re then im)
  {
    float* L = lbuf + c * 273;
#pragma unroll
    for (int k1 = 0; k1 < 16; ++k1) L[k1 * 17 + t] = a[k1].re;
    __syncthreads();
    float br[16];
#pragma unroll
    for (int n2 = 0; n2 < 16; ++n2) br[n2] = L[t * 17 + n2];
    __syncthreads();
#pragma unroll
    for (int k1 = 0; k1 < 16; ++k1) L[k1 * 17 + t] = a[k1].im;
    __syncthreads();
#pragma unroll
    for (int n2 = 0; n2 < 16; ++n2) { a[n2].im = L[t * 17 + n2]; a[n2].re = br[n2]; }
  }

  ifft16(a);
  constexpr float sc = 1.0f / 256.0f;         // second half of the norm
#pragma unroll
  for (int k = 0; k < 16; ++k) {
    const int m = (((k << 4) | t) ^ 128);     // fftshift on store
    __builtin_nontemporal_store(a[k].re * sc, &yr[base + m * NN]);
    __builtin_nontemporal_store(a[k].im * sc, &yi[base + m * NN]);
  }
}

} // namespace

extern "C" void kernel_launch(void* const* d_in, const int* in_sizes, int n_in,
                              void* d_out, int out_size, void* d_ws, size_t ws_size,
                              hipStream_t stream) {
  const float* xr = (const float*)d_in[0];
  const float* xi = (const float*)d_in[1];
  float* yr = (float*)d_out;        // real part of output
  float* yi = yr + BMN;             // imag part of output
  __half* wr = (__half*)d_ws;       // fp16 intermediate (67 MB, fits 512MiB ws)
  __half* wi = wr + BMN;

  k_ifft_rows<<<4096, 256, 0, stream>>>(xr, xi, wr, wi);       // 65536 lines / 16
  k_ifft_cols<<<2048, 512, 0, stream>>>(wr, wi, yr, yi);       // 256 images * 8 tiles
}